// Round 1
// baseline (267.118 us; speedup 1.0000x reference)
//
#include <hip/hip_runtime.h>
#include <hip/hip_bf16.h>
#include <stdint.h>

#define SEQ 4096
#define DM 512
#define NH 8
#define HD 64
#define WIN 65

typedef __attribute__((ext_vector_type(8))) short bf16x8;
typedef __attribute__((ext_vector_type(4))) float f32x4;

__device__ __forceinline__ unsigned short f2bf(float f) {
  unsigned int u = __float_as_uint(f);
  u += 0x7FFFu + ((u >> 16) & 1u);
  return (unsigned short)(u >> 16);
}
__device__ __forceinline__ float bf2f(unsigned short h) {
  return __uint_as_float(((unsigned int)h) << 16);
}
__device__ __forceinline__ float bflo(unsigned int u) { return __uint_as_float(u << 16); }
__device__ __forceinline__ float bfhi(unsigned int u) { return __uint_as_float(u & 0xFFFF0000u); }

// ---- convert x (f32) -> bf16 ----
__global__ void conv_x_kernel(const float* __restrict__ x, unsigned short* __restrict__ xb, int n4) {
  int i = blockIdx.x * blockDim.x + threadIdx.x;
  if (i < n4) {
    float4 v = ((const float4*)x)[i];
    ushort4 o;
    o.x = f2bf(v.x); o.y = f2bf(v.y); o.z = f2bf(v.z); o.w = f2bf(v.w);
    ((ushort4*)xb)[i] = o;
  }
}

// ---- transpose + convert W (512x512 f32, k-major) -> Wt (n-major bf16) ----
__global__ void conv_wt_kernel(const float* __restrict__ w0, const float* __restrict__ w1,
                               const float* __restrict__ w2, const float* __restrict__ w3,
                               unsigned short* __restrict__ wt) {
  __shared__ float tl[64][65];
  const int z = blockIdx.z;
  const float* W = (z == 0) ? w0 : (z == 1) ? w1 : (z == 2) ? w2 : w3;
  unsigned short* o = wt + (size_t)z * 262144;
  const int k0 = blockIdx.x * 64;
  const int n0 = blockIdx.y * 64;
  const int t = threadIdx.x;
#pragma unroll
  for (int i = 0; i < 16; ++i) {
    int idx = t + i * 256;
    int r = idx >> 6, c = idx & 63;
    tl[c][r] = W[(size_t)(k0 + r) * 512 + n0 + c];
  }
  __syncthreads();
#pragma unroll
  for (int i = 0; i < 16; ++i) {
    int idx = t + i * 256;
    int r = idx >> 6, c = idx & 63;
    o[(size_t)(n0 + r) * 512 + k0 + c] = f2bf(tl[r][c]);
  }
}

// ---- bf16 MFMA GEMM: C(8192x512) = A(8192x512) @ W^T(stored n-major) + bias ----
// MODE 0: z in {0,1,2} selects Wq/Wk/Wv; output scattered to (B*H, N, 64) bf16.
// MODE 1: Wo; output f32 row-major (B*N, 512).
template <int MODE>
__global__ __launch_bounds__(256) void gemm_kernel(
    const unsigned short* __restrict__ A,
    const unsigned short* __restrict__ wt,
    const float* __restrict__ b0, const float* __restrict__ b1, const float* __restrict__ b2,
    void* __restrict__ outp) {
  const int z = (MODE == 0) ? blockIdx.z : 0;
  const unsigned short* W = wt + (size_t)z * 262144;
  const float* bias = (MODE == 0) ? ((z == 0) ? b0 : (z == 1) ? b1 : b2) : b0;

  __shared__ unsigned short As[128 * 40];
  __shared__ unsigned short Bs[128 * 40];

  const int t = threadIdx.x;
  const int lane = t & 63;
  const int wv = t >> 6;
  const int wr = wv >> 1, wc = wv & 1;
  const int l15 = lane & 15, l4 = lane >> 4;

  const int bm0 = blockIdx.x * 128;
  const int bn0 = blockIdx.y * 128;

  f32x4 acc[4][4];
#pragma unroll
  for (int i = 0; i < 4; ++i)
#pragma unroll
    for (int j = 0; j < 4; ++j) acc[i][j] = (f32x4){0.f, 0.f, 0.f, 0.f};

  const int sr0 = t >> 2;        // 0..63
  const int sc = (t & 3) * 8;    // 0,8,16,24

  for (int kt = 0; kt < 512; kt += 32) {
    __syncthreads();
    {
      const uint4 a0 = *(const uint4*)&A[(size_t)(bm0 + sr0) * 512 + kt + sc];
      const uint4 a1 = *(const uint4*)&A[(size_t)(bm0 + sr0 + 64) * 512 + kt + sc];
      *(uint4*)&As[sr0 * 40 + sc] = a0;
      *(uint4*)&As[(sr0 + 64) * 40 + sc] = a1;
      const uint4 w0 = *(const uint4*)&W[(size_t)(bn0 + sr0) * 512 + kt + sc];
      const uint4 w1 = *(const uint4*)&W[(size_t)(bn0 + sr0 + 64) * 512 + kt + sc];
      *(uint4*)&Bs[sr0 * 40 + sc] = w0;
      *(uint4*)&Bs[(sr0 + 64) * 40 + sc] = w1;
    }
    __syncthreads();
    bf16x8 af[4], bfr[4];
#pragma unroll
    for (int mi = 0; mi < 4; ++mi)
      af[mi] = *(const bf16x8*)&As[(wr * 64 + mi * 16 + l15) * 40 + l4 * 8];
#pragma unroll
    for (int ni = 0; ni < 4; ++ni)
      bfr[ni] = *(const bf16x8*)&Bs[(wc * 64 + ni * 16 + l15) * 40 + l4 * 8];
#pragma unroll
    for (int mi = 0; mi < 4; ++mi)
#pragma unroll
      for (int ni = 0; ni < 4; ++ni)
        acc[mi][ni] = __builtin_amdgcn_mfma_f32_16x16x32_bf16(af[mi], bfr[ni], acc[mi][ni], 0, 0, 0);
  }

#pragma unroll
  for (int mi = 0; mi < 4; ++mi) {
#pragma unroll
    for (int ni = 0; ni < 4; ++ni) {
      const int gn = bn0 + wc * 64 + ni * 16 + l15;
      const float bb = bias[gn];
#pragma unroll
      for (int j = 0; j < 4; ++j) {
        const int gm = bm0 + wr * 64 + mi * 16 + l4 * 4 + j;
        const float val = acc[mi][ni][j] + bb;
        if (MODE == 0) {
          const int b = gm >> 12;      // / 4096
          const int nn = gm & 4095;
          const int h = gn >> 6;
          const int dd = gn & 63;
          unsigned short* op = (unsigned short*)outp + (size_t)z * 4194304;
          op[(((size_t)(b * NH + h) * SEQ) + nn) * HD + dd] = f2bf(val);
        } else {
          float* op = (float*)outp;
          op[(size_t)gm * 512 + gn] = val;
        }
      }
    }
  }
}

// ---- local attention: one wave per (bh, n) ----
__global__ __launch_bounds__(256) void attn_kernel(
    const unsigned short* __restrict__ qb, const unsigned short* __restrict__ kb,
    const unsigned short* __restrict__ vb,
    float* __restrict__ attn_out, unsigned short* __restrict__ ctxb) {
  __shared__ float qs[4][64];
  __shared__ float aw[4][WIN];
  const int t = threadIdx.x;
  const int lane = t & 63;
  const int wv = t >> 6;
  const int bh = blockIdx.y;
  const int n = blockIdx.x * 4 + wv;
  const size_t base = (size_t)bh * SEQ;

  const float qv = bf2f(qb[(base + n) * HD + lane]);
  qs[wv][lane] = qv;
  __syncthreads();

  // w = 64 score (kidx = n + 32), via wave reduction
  float s64 = 0.f;
  {
    int kidx = n + 32;
    if (kidx < SEQ) {
      float p = bf2f(kb[(base + kidx) * HD + lane]) * qv;
#pragma unroll
      for (int o = 32; o > 0; o >>= 1) p += __shfl_xor(p, o);
      s64 = p * 0.125f;
    }
  }
  // lane-parallel scores, w = lane in [0,64)
  float s = 0.f;
  {
    int kidx = n + lane - 32;
    if (kidx >= 0 && kidx < SEQ) {
      const uint4* kr = (const uint4*)&kb[(base + kidx) * HD];
      float acc = 0.f;
#pragma unroll
      for (int d8 = 0; d8 < 8; ++d8) {
        uint4 kv = kr[d8];
        acc += bflo(kv.x) * qs[wv][d8 * 8 + 0];
        acc += bfhi(kv.x) * qs[wv][d8 * 8 + 1];
        acc += bflo(kv.y) * qs[wv][d8 * 8 + 2];
        acc += bfhi(kv.y) * qs[wv][d8 * 8 + 3];
        acc += bflo(kv.z) * qs[wv][d8 * 8 + 4];
        acc += bfhi(kv.z) * qs[wv][d8 * 8 + 5];
        acc += bflo(kv.w) * qs[wv][d8 * 8 + 6];
        acc += bfhi(kv.w) * qs[wv][d8 * 8 + 7];
      }
      s = acc * 0.125f;
    }
  }
  // softmax over 65 values (OOB scores are exactly 0, matching the zero-pad reference)
  float m = fmaxf(s, s64);
#pragma unroll
  for (int o = 32; o > 0; o >>= 1) m = fmaxf(m, __shfl_xor(m, o));
  const float p = expf(s - m);
  const float p64 = expf(s64 - m);
  float sum = p;
#pragma unroll
  for (int o = 32; o > 0; o >>= 1) sum += __shfl_xor(sum, o);
  sum += p64;
  const float inv = 1.f / sum;
  const float a_l = p * inv;
  const float a64 = p64 * inv;

  float* ao = &attn_out[(base + n) * WIN];
  ao[lane] = a_l;
  if (lane == 0) ao[64] = a64;
  aw[wv][lane] = a_l;
  if (lane == 0) aw[wv][64] = a64;
  __syncthreads();

  // PV: lane = d
  float ctx = 0.f;
  for (int w = 0; w < WIN; ++w) {
    int kidx = n + w - 32;
    if (kidx >= 0 && kidx < SEQ) {
      ctx += aw[wv][w] * bf2f(vb[(base + kidx) * HD + lane]);
    }
  }
  const int b = bh >> 3, h = bh & 7;
  ctxb[((size_t)(b * SEQ + n)) * DM + h * HD + lane] = f2bf(ctx);
}

extern "C" void kernel_launch(void* const* d_in, const int* in_sizes, int n_in,
                              void* d_out, int out_size, void* d_ws, size_t ws_size,
                              hipStream_t stream) {
  const float* x  = (const float*)d_in[0];
  const float* Wq = (const float*)d_in[1];
  const float* Wk = (const float*)d_in[2];
  const float* Wv = (const float*)d_in[3];
  const float* Wo = (const float*)d_in[4];
  const float* bq = (const float*)d_in[5];
  const float* bk = (const float*)d_in[6];
  const float* bv = (const float*)d_in[7];
  const float* bo = (const float*)d_in[8];

  float* out = (float*)d_out;                        // (B, N, 512) f32
  float* attn_out = out + (size_t)8192 * 512;        // (B, H, N, 65) f32

  char* ws = (char*)d_ws;
  unsigned short* xb   = (unsigned short*)ws;                       // 8,388,608 B
  unsigned short* wt   = (unsigned short*)(ws + 8388608);           // 2,097,152 B (Wq,Wk,Wv,Wo transposed bf16)
  unsigned short* qkv  = (unsigned short*)(ws + 10485760);          // 25,165,824 B (q,k,v bf16, head-major)
  unsigned short* ctxb = (unsigned short*)(ws + 35651584);          // 8,388,608 B (ctx bf16, (B,N,512))

  conv_x_kernel<<<dim3(4096), dim3(256), 0, stream>>>(x, xb, 1048576);
  conv_wt_kernel<<<dim3(8, 8, 4), dim3(256), 0, stream>>>(Wq, Wk, Wv, Wo, wt);
  gemm_kernel<0><<<dim3(64, 4, 3), dim3(256), 0, stream>>>(xb, wt, bq, bk, bv, (void*)qkv);
  attn_kernel<<<dim3(1024, 16), dim3(256), 0, stream>>>(
      qkv, qkv + 4194304, qkv + 8388608, attn_out, ctxb);
  gemm_kernel<1><<<dim3(64, 4, 1), dim3(256), 0, stream>>>(ctxb, wt + 3 * 262144, bo, nullptr, nullptr, (void*)out);
}

// Round 2
// 77.113 us; speedup vs baseline: 3.4640x; 3.4640x over previous
//
#include <hip/hip_runtime.h>
#include <hip/hip_bf16.h>
#include <stdint.h>

#define SEQ 4096
#define DM 512
#define NH 8
#define HD 64
#define WIN 65

typedef __attribute__((ext_vector_type(8))) short bf16x8;
typedef __attribute__((ext_vector_type(4))) float f32x4;

__device__ __forceinline__ unsigned short f2bf(float f) {
  unsigned int u = __float_as_uint(f);
  u += 0x7FFFu + ((u >> 16) & 1u);
  return (unsigned short)(u >> 16);
}
__device__ __forceinline__ float bf2f(unsigned short h) {
  return __uint_as_float(((unsigned int)h) << 16);
}

// ---- convert x (f32) -> bf16 ----
__global__ void conv_x_kernel(const float* __restrict__ x, unsigned short* __restrict__ xb, int n4) {
  int i = blockIdx.x * blockDim.x + threadIdx.x;
  if (i < n4) {
    float4 v = ((const float4*)x)[i];
    ushort4 o;
    o.x = f2bf(v.x); o.y = f2bf(v.y); o.z = f2bf(v.z); o.w = f2bf(v.w);
    ((ushort4*)xb)[i] = o;
  }
}

// ---- transpose + convert W (512x512 f32, k-major) -> Wt (n-major bf16) ----
__global__ void conv_wt_kernel(const float* __restrict__ w0, const float* __restrict__ w1,
                               const float* __restrict__ w2, const float* __restrict__ w3,
                               unsigned short* __restrict__ wt) {
  __shared__ float tl[64][65];
  const int z = blockIdx.z;
  const float* W = (z == 0) ? w0 : (z == 1) ? w1 : (z == 2) ? w2 : w3;
  unsigned short* o = wt + (size_t)z * 262144;
  const int k0 = blockIdx.x * 64;
  const int n0 = blockIdx.y * 64;
  const int t = threadIdx.x;
#pragma unroll
  for (int i = 0; i < 16; ++i) {
    int idx = t + i * 256;
    int r = idx >> 6, c = idx & 63;
    tl[c][r] = W[(size_t)(k0 + r) * 512 + n0 + c];
  }
  __syncthreads();
#pragma unroll
  for (int i = 0; i < 16; ++i) {
    int idx = t + i * 256;
    int r = idx >> 6, c = idx & 63;
    o[(size_t)(n0 + r) * 512 + k0 + c] = f2bf(tl[r][c]);
  }
}

// ---- bf16 MFMA GEMM: C(8192x512) = A(8192x512) @ W^T(stored n-major) + bias ----
// MODE 0: z in {0,1,2} selects Wq/Wk/Wv; q,k -> (B*H, N, 64) bf16; v -> transposed (B*H, 64, N) bf16.
// MODE 1: Wo; output f32 row-major (B*N, 512).
template <int MODE>
__global__ __launch_bounds__(256) void gemm_kernel(
    const unsigned short* __restrict__ A,
    const unsigned short* __restrict__ wt,
    const float* __restrict__ b0, const float* __restrict__ b1, const float* __restrict__ b2,
    void* __restrict__ outp) {
  const int z = (MODE == 0) ? blockIdx.z : 0;
  const unsigned short* W = wt + (size_t)z * 262144;
  const float* bias = (MODE == 0) ? ((z == 0) ? b0 : (z == 1) ? b1 : b2) : b0;

  __shared__ unsigned short As[128 * 40];
  __shared__ unsigned short Bs[128 * 40];

  const int t = threadIdx.x;
  const int lane = t & 63;
  const int wv = t >> 6;
  const int wr = wv >> 1, wc = wv & 1;
  const int l15 = lane & 15, l4 = lane >> 4;

  const int bm0 = blockIdx.x * 128;
  const int bn0 = blockIdx.y * 128;

  f32x4 acc[4][4];
#pragma unroll
  for (int i = 0; i < 4; ++i)
#pragma unroll
    for (int j = 0; j < 4; ++j) acc[i][j] = (f32x4){0.f, 0.f, 0.f, 0.f};

  const int sr0 = t >> 2;        // 0..63
  const int sc = (t & 3) * 8;    // 0,8,16,24

  for (int kt = 0; kt < 512; kt += 32) {
    __syncthreads();
    {
      const uint4 a0 = *(const uint4*)&A[(size_t)(bm0 + sr0) * 512 + kt + sc];
      const uint4 a1 = *(const uint4*)&A[(size_t)(bm0 + sr0 + 64) * 512 + kt + sc];
      *(uint4*)&As[sr0 * 40 + sc] = a0;
      *(uint4*)&As[(sr0 + 64) * 40 + sc] = a1;
      const uint4 w0 = *(const uint4*)&W[(size_t)(bn0 + sr0) * 512 + kt + sc];
      const uint4 w1 = *(const uint4*)&W[(size_t)(bn0 + sr0 + 64) * 512 + kt + sc];
      *(uint4*)&Bs[sr0 * 40 + sc] = w0;
      *(uint4*)&Bs[(sr0 + 64) * 40 + sc] = w1;
    }
    __syncthreads();
    bf16x8 af[4], bfr[4];
#pragma unroll
    for (int mi = 0; mi < 4; ++mi)
      af[mi] = *(const bf16x8*)&As[(wr * 64 + mi * 16 + l15) * 40 + l4 * 8];
#pragma unroll
    for (int ni = 0; ni < 4; ++ni)
      bfr[ni] = *(const bf16x8*)&Bs[(wc * 64 + ni * 16 + l15) * 40 + l4 * 8];
#pragma unroll
    for (int mi = 0; mi < 4; ++mi)
#pragma unroll
      for (int ni = 0; ni < 4; ++ni)
        acc[mi][ni] = __builtin_amdgcn_mfma_f32_16x16x32_bf16(af[mi], bfr[ni], acc[mi][ni], 0, 0, 0);
  }

#pragma unroll
  for (int mi = 0; mi < 4; ++mi) {
#pragma unroll
    for (int ni = 0; ni < 4; ++ni) {
      const int gn = bn0 + wc * 64 + ni * 16 + l15;
      const float bb = bias[gn];
      if (MODE == 0 && z == 2) {
        // V transposed: (B*H, 64, N) so attention PV B-fragments are contiguous
        ushort4 o4;
        o4.x = f2bf(acc[mi][ni][0] + bb);
        o4.y = f2bf(acc[mi][ni][1] + bb);
        o4.z = f2bf(acc[mi][ni][2] + bb);
        o4.w = f2bf(acc[mi][ni][3] + bb);
        const int gm0 = bm0 + wr * 64 + mi * 16 + l4 * 4;
        const int b = gm0 >> 12;
        const int nn = gm0 & 4095;
        const int h = gn >> 6;
        const int dd = gn & 63;
        unsigned short* op = (unsigned short*)outp + (size_t)2 * 4194304;
        *(ushort4*)&op[((size_t)(b * NH + h) * HD + dd) * SEQ + nn] = o4;
      } else {
#pragma unroll
        for (int j = 0; j < 4; ++j) {
          const int gm = bm0 + wr * 64 + mi * 16 + l4 * 4 + j;
          const float val = acc[mi][ni][j] + bb;
          if (MODE == 0) {
            const int b = gm >> 12;      // / 4096
            const int nn = gm & 4095;
            const int h = gn >> 6;
            const int dd = gn & 63;
            unsigned short* op = (unsigned short*)outp + (size_t)z * 4194304;
            op[(((size_t)(b * NH + h) * SEQ) + nn) * HD + dd] = f2bf(val);
          } else {
            float* op = (float*)outp;
            op[(size_t)gm * 512 + gn] = val;
          }
        }
      }
    }
  }
}

// ---- MFMA local attention ----
// Block: 512 threads = 8 waves; each wave owns 16 queries (sub-tile).
// Per wave: banded QK^T (16 queries x 80 k-rows, 10 MFMAs), softmax in
// C-fragment registers, P -> LDS relayout, PV (16x96x64, 12 MFMAs).
// OOB pad positions: K/V fragments zeroed -> score exactly 0, V contribution 0
// (matches the reference's zero-padding; those positions ARE in the softmax).
__global__ __launch_bounds__(512) void attn_kernel(
    const unsigned short* __restrict__ qb, const unsigned short* __restrict__ kb,
    const unsigned short* __restrict__ vt,
    float* __restrict__ attn_out, unsigned short* __restrict__ ctxb) {
  __shared__ unsigned short Plds[8][16][104];   // stride 208B = 13*16B: aligned, conflict-light
  const int t = threadIdx.x;
  const int lane = t & 63;
  const int wv = t >> 6;
  const int l15 = lane & 15;
  const int g = lane >> 4;
  const int bh = blockIdx.y;
  const int n0 = blockIdx.x * 128;
  const int i0 = wv * 16;
  const int q0 = n0 + i0;
  const size_t qkbase = (size_t)bh * SEQ * HD;

  // ---- QK^T: S[i][c] for c in [0,80), k-row = q0-32+c ----
  bf16x8 aq[2];
#pragma unroll
  for (int kc = 0; kc < 2; ++kc)
    aq[kc] = *(const bf16x8*)&qb[qkbase + (size_t)(q0 + l15) * HD + kc * 32 + g * 8];

  f32x4 accs[5];
#pragma unroll
  for (int tt = 0; tt < 5; ++tt) accs[tt] = (f32x4){0.f, 0.f, 0.f, 0.f};

#pragma unroll
  for (int tt = 0; tt < 5; ++tt) {
    const int krow = q0 - 32 + tt * 16 + l15;
    bf16x8 bk0 = (bf16x8){0, 0, 0, 0, 0, 0, 0, 0};
    bf16x8 bk1 = bk0;
    if (krow >= 0 && krow < SEQ) {
      bk0 = *(const bf16x8*)&kb[qkbase + (size_t)krow * HD + g * 8];
      bk1 = *(const bf16x8*)&kb[qkbase + (size_t)krow * HD + 32 + g * 8];
    }
    accs[tt] = __builtin_amdgcn_mfma_f32_16x16x32_bf16(aq[0], bk0, accs[tt], 0, 0, 0);
    accs[tt] = __builtin_amdgcn_mfma_f32_16x16x32_bf16(aq[1], bk1, accs[tt], 0, 0, 0);
  }

  // ---- softmax over w = c - i in [0,64]; C layout: col c = 16t+l15, row i = 4g+j ----
#pragma unroll
  for (int tt = 0; tt < 5; ++tt)
#pragma unroll
    for (int j = 0; j < 4; ++j) {
      const int w = tt * 16 + l15 - (4 * g + j);
      accs[tt][j] = (w >= 0 && w <= 64) ? accs[tt][j] * 0.125f : -3.0e38f;
    }
  float mj[4], invj[4];
#pragma unroll
  for (int j = 0; j < 4; ++j) {
    float m = fmaxf(fmaxf(fmaxf(accs[0][j], accs[1][j]), fmaxf(accs[2][j], accs[3][j])), accs[4][j]);
#pragma unroll
    for (int o = 8; o; o >>= 1) m = fmaxf(m, __shfl_xor(m, o));
    mj[j] = m;
  }
#pragma unroll
  for (int tt = 0; tt < 5; ++tt)
#pragma unroll
    for (int j = 0; j < 4; ++j)
      accs[tt][j] = (accs[tt][j] > -1.0e38f) ? __expf(accs[tt][j] - mj[j]) : 0.f;
#pragma unroll
  for (int j = 0; j < 4; ++j) {
    float s = accs[0][j] + accs[1][j] + accs[2][j] + accs[3][j] + accs[4][j];
#pragma unroll
    for (int o = 8; o; o >>= 1) s += __shfl_xor(s, o);
    invj[j] = 1.f / s;
  }
  const size_t abase = (size_t)bh * SEQ;
#pragma unroll
  for (int tt = 0; tt < 5; ++tt)
#pragma unroll
    for (int j = 0; j < 4; ++j) {
      const int i = 4 * g + j;
      const int w = tt * 16 + l15 - i;
      const float a = accs[tt][j] * invj[j];
      if (w >= 0 && w <= 64)
        attn_out[(abase + q0 + i) * WIN + w] = a;
      Plds[wv][i][tt * 16 + l15] = f2bf(a);
    }
#pragma unroll
  for (int j = 0; j < 4; ++j) Plds[wv][4 * g + j][80 + l15] = 0;

  // ---- PV: ctx[i][d] = sum_c P[i][c] * V[q0-32+c][d], via VT (bh,d,n) ----
  f32x4 accc[4];
#pragma unroll
  for (int dt = 0; dt < 4; ++dt) accc[dt] = (f32x4){0.f, 0.f, 0.f, 0.f};
#pragma unroll
  for (int kc = 0; kc < 3; ++kc) {
    const bf16x8 pa = *(const bf16x8*)&Plds[wv][l15][kc * 32 + g * 8];
    const int nb = q0 - 32 + kc * 32 + g * 8;   // multiple of 8: chunks all-in or all-out
    const bool inr = (nb >= 0 && nb < SEQ);
#pragma unroll
    for (int dt = 0; dt < 4; ++dt) {
      bf16x8 bv = (bf16x8){0, 0, 0, 0, 0, 0, 0, 0};
      if (inr) bv = *(const bf16x8*)&vt[((size_t)bh * HD + dt * 16 + l15) * SEQ + nb];
      accc[dt] = __builtin_amdgcn_mfma_f32_16x16x32_bf16(pa, bv, accc[dt], 0, 0, 0);
    }
  }
  const int b = bh >> 3, h = bh & 7;
#pragma unroll
  for (int dt = 0; dt < 4; ++dt)
#pragma unroll
    for (int j = 0; j < 4; ++j)
      ctxb[((size_t)(b * SEQ + q0 + 4 * g + j)) * DM + h * HD + dt * 16 + l15] = f2bf(accc[dt][j]);
}

extern "C" void kernel_launch(void* const* d_in, const int* in_sizes, int n_in,
                              void* d_out, int out_size, void* d_ws, size_t ws_size,
                              hipStream_t stream) {
  const float* x  = (const float*)d_in[0];
  const float* Wq = (const float*)d_in[1];
  const float* Wk = (const float*)d_in[2];
  const float* Wv = (const float*)d_in[3];
  const float* Wo = (const float*)d_in[4];
  const float* bq = (const float*)d_in[5];
  const float* bk = (const float*)d_in[6];
  const float* bv = (const float*)d_in[7];
  const float* bo = (const float*)d_in[8];

  float* out = (float*)d_out;                        // (B, N, 512) f32
  float* attn_out = out + (size_t)8192 * 512;        // (B, H, N, 65) f32

  char* ws = (char*)d_ws;
  unsigned short* xb   = (unsigned short*)ws;                       // 8,388,608 B
  unsigned short* wt   = (unsigned short*)(ws + 8388608);           // 2,097,152 B (Wq,Wk,Wv,Wo transposed bf16)
  unsigned short* qkv  = (unsigned short*)(ws + 10485760);          // 25,165,824 B (q,k bf16 head-major; vt transposed)
  unsigned short* ctxb = (unsigned short*)(ws + 35651584);          // 8,388,608 B (ctx bf16, (B,N,512))

  conv_x_kernel<<<dim3(4096), dim3(256), 0, stream>>>(x, xb, 1048576);
  conv_wt_kernel<<<dim3(8, 8, 4), dim3(256), 0, stream>>>(Wq, Wk, Wv, Wo, wt);
  gemm_kernel<0><<<dim3(64, 4, 3), dim3(256), 0, stream>>>(xb, wt, bq, bk, bv, (void*)qkv);
  attn_kernel<<<dim3(32, 16), dim3(512), 0, stream>>>(
      qkv, qkv + 4194304, qkv + 8388608, attn_out, ctxb);
  gemm_kernel<1><<<dim3(64, 4, 1), dim3(256), 0, stream>>>(ctxb, wt + 3 * 262144, bo, nullptr, nullptr, (void*)out);
}

// Round 3
// 73.911 us; speedup vs baseline: 3.6141x; 1.0433x over previous
//
#include <hip/hip_runtime.h>
#include <hip/hip_bf16.h>
#include <stdint.h>

#define SEQ 4096
#define DM 512
#define NH 8
#define HD 64
#define WIN 65

typedef __attribute__((ext_vector_type(8))) short bf16x8;
typedef __attribute__((ext_vector_type(4))) float f32x4;

#define GLOAD_LDS16(gp, lp)                                                 \
  __builtin_amdgcn_global_load_lds(                                         \
      (const __attribute__((address_space(1))) void*)(gp),                  \
      (__attribute__((address_space(3))) void*)(lp), 16, 0, 0)

__device__ __forceinline__ unsigned short f2bf(float f) {
  unsigned int u = __float_as_uint(f);
  u += 0x7FFFu + ((u >> 16) & 1u);
  return (unsigned short)(u >> 16);
}
__device__ __forceinline__ float bf2f(unsigned short h) {
  return __uint_as_float(((unsigned int)h) << 16);
}

// ---- convert x (f32) -> bf16 ----
__global__ void conv_x_kernel(const float* __restrict__ x, unsigned short* __restrict__ xb, int n4) {
  int i = blockIdx.x * blockDim.x + threadIdx.x;
  if (i < n4) {
    float4 v = ((const float4*)x)[i];
    ushort4 o;
    o.x = f2bf(v.x); o.y = f2bf(v.y); o.z = f2bf(v.z); o.w = f2bf(v.w);
    ((ushort4*)xb)[i] = o;
  }
}

// ---- transpose + convert W (512x512 f32, k-major) -> Wt (n-major bf16) ----
__global__ void conv_wt_kernel(const float* __restrict__ w0, const float* __restrict__ w1,
                               const float* __restrict__ w2, const float* __restrict__ w3,
                               unsigned short* __restrict__ wt) {
  __shared__ float tl[64][65];
  const int z = blockIdx.z;
  const float* W = (z == 0) ? w0 : (z == 1) ? w1 : (z == 2) ? w2 : w3;
  unsigned short* o = wt + (size_t)z * 262144;
  const int k0 = blockIdx.x * 64;
  const int n0 = blockIdx.y * 64;
  const int t = threadIdx.x;
#pragma unroll
  for (int i = 0; i < 16; ++i) {
    int idx = t + i * 256;
    int r = idx >> 6, c = idx & 63;
    tl[c][r] = W[(size_t)(k0 + r) * 512 + n0 + c];
  }
  __syncthreads();
#pragma unroll
  for (int i = 0; i < 16; ++i) {
    int idx = t + i * 256;
    int r = idx >> 6, c = idx & 63;
    o[(size_t)(n0 + r) * 512 + k0 + c] = f2bf(tl[r][c]);
  }
}

// ---- bf16 MFMA GEMM with global_load_lds(16B) staging, linear LDS [128][32] ----
// MODE 0: z in {0,1,2} selects Wq/Wk/Wv; q (pre-scaled by 1/8), k -> (B*H, N, 64) bf16;
//         v -> transposed (B*H, 64, N) bf16.
// MODE 1: Wo; output f32 row-major (B*N, 512).
template <int MODE>
__global__ __launch_bounds__(256) void gemm_kernel(
    const unsigned short* __restrict__ A,
    const unsigned short* __restrict__ wt,
    const float* __restrict__ b0, const float* __restrict__ b1, const float* __restrict__ b2,
    void* __restrict__ outp) {
  const int z = (MODE == 0) ? blockIdx.z : 0;
  const unsigned short* W = wt + (size_t)z * 262144;
  const float* bias = (MODE == 0) ? ((z == 0) ? b0 : (z == 1) ? b1 : b2) : b0;

  __shared__ unsigned short As[128 * 32];
  __shared__ unsigned short Bs[128 * 32];

  const int t = threadIdx.x;
  const int lane = t & 63;
  const int wv = t >> 6;
  const int wr = wv >> 1, wc = wv & 1;
  const int l15 = lane & 15, l4 = lane >> 4;

  const int bm0 = blockIdx.x * 128;
  const int bn0 = blockIdx.y * 128;

  // staging geometry: chunk c = wv*2+s covers LDS rows c*16..c*16+15 (64B/row);
  // lane i -> row c*16 + i/4, col-bytes (i&3)*16.  HW writes LDS at base + lane*16.
  const int srow = wv * 32 + (lane >> 2);
  const int scol = (lane & 3) * 8;
  const unsigned short* Ap0 = A + (size_t)(bm0 + srow) * 512 + scol;
  const unsigned short* Ap1 = Ap0 + (size_t)16 * 512;
  const unsigned short* Bp0 = W + (size_t)(bn0 + srow) * 512 + scol;
  const unsigned short* Bp1 = Bp0 + (size_t)16 * 512;
  unsigned short* lA0 = &As[(wv * 2 + 0) * 512];
  unsigned short* lA1 = &As[(wv * 2 + 1) * 512];
  unsigned short* lB0 = &Bs[(wv * 2 + 0) * 512];
  unsigned short* lB1 = &Bs[(wv * 2 + 1) * 512];

  f32x4 acc[4][4];
#pragma unroll
  for (int i = 0; i < 4; ++i)
#pragma unroll
    for (int j = 0; j < 4; ++j) acc[i][j] = (f32x4){0.f, 0.f, 0.f, 0.f};

  for (int kt = 0; kt < 512; kt += 32) {
    __syncthreads();
    GLOAD_LDS16(Ap0 + kt, lA0);
    GLOAD_LDS16(Ap1 + kt, lA1);
    GLOAD_LDS16(Bp0 + kt, lB0);
    GLOAD_LDS16(Bp1 + kt, lB1);
    __syncthreads();   // drains vmcnt(0) before barrier -> staged data visible
    bf16x8 af[4], bfr[4];
#pragma unroll
    for (int mi = 0; mi < 4; ++mi)
      af[mi] = *(const bf16x8*)&As[(wr * 64 + mi * 16 + l15) * 32 + l4 * 8];
#pragma unroll
    for (int ni = 0; ni < 4; ++ni)
      bfr[ni] = *(const bf16x8*)&Bs[(wc * 64 + ni * 16 + l15) * 32 + l4 * 8];
#pragma unroll
    for (int mi = 0; mi < 4; ++mi)
#pragma unroll
      for (int ni = 0; ni < 4; ++ni)
        acc[mi][ni] = __builtin_amdgcn_mfma_f32_16x16x32_bf16(af[mi], bfr[ni], acc[mi][ni], 0, 0, 0);
  }

  const float sc = (MODE == 0 && z == 0) ? 0.125f : 1.0f;
#pragma unroll
  for (int mi = 0; mi < 4; ++mi) {
#pragma unroll
    for (int ni = 0; ni < 4; ++ni) {
      const int gn = bn0 + wc * 64 + ni * 16 + l15;
      const float bb = bias[gn];
      if (MODE == 0 && z == 2) {
        // V transposed: (B*H, 64, N) so attention PV B-fragments are contiguous
        ushort4 o4;
        o4.x = f2bf(acc[mi][ni][0] + bb);
        o4.y = f2bf(acc[mi][ni][1] + bb);
        o4.z = f2bf(acc[mi][ni][2] + bb);
        o4.w = f2bf(acc[mi][ni][3] + bb);
        const int gm0 = bm0 + wr * 64 + mi * 16 + l4 * 4;
        const int b = gm0 >> 12;
        const int nn = gm0 & 4095;
        const int h = gn >> 6;
        const int dd = gn & 63;
        unsigned short* op = (unsigned short*)outp + (size_t)2 * 4194304;
        *(ushort4*)&op[((size_t)(b * NH + h) * HD + dd) * SEQ + nn] = o4;
      } else {
#pragma unroll
        for (int j = 0; j < 4; ++j) {
          const int gm = bm0 + wr * 64 + mi * 16 + l4 * 4 + j;
          const float val = (acc[mi][ni][j] + bb) * sc;
          if (MODE == 0) {
            const int b = gm >> 12;      // / 4096
            const int nn = gm & 4095;
            const int h = gn >> 6;
            const int dd = gn & 63;
            unsigned short* op = (unsigned short*)outp + (size_t)z * 4194304;
            op[(((size_t)(b * NH + h) * SEQ) + nn) * HD + dd] = f2bf(val);
          } else {
            float* op = (float*)outp;
            op[(size_t)gm * 512 + gn] = val;
          }
        }
      }
    }
  }
}

// ---- MFMA local attention ----
// Block: 512 threads = 8 waves; each wave owns 16 queries.
// QK^T banded strip (10 MFMAs), softmax in C-fragment registers, P->LDS
// relayout, PV (12 MFMAs) against transposed V. q pre-scaled by 1/8.
__global__ __launch_bounds__(512) void attn_kernel(
    const unsigned short* __restrict__ qb, const unsigned short* __restrict__ kb,
    const unsigned short* __restrict__ vt,
    float* __restrict__ attn_out, unsigned short* __restrict__ ctxb) {
  __shared__ unsigned short Plds[8][16][104];   // stride 208B: 16B-aligned, conflict-light
  const int t = threadIdx.x;
  const int lane = t & 63;
  const int wv = t >> 6;
  const int l15 = lane & 15;
  const int g = lane >> 4;
  const int bh = blockIdx.y;
  const int n0 = blockIdx.x * 128;
  const int q0 = n0 + wv * 16;
  const size_t qkbase = (size_t)bh * SEQ * HD;

  // ---- QK^T: S[i][c] for c in [0,80), k-row = q0-32+c ----
  bf16x8 aq[2];
#pragma unroll
  for (int kc = 0; kc < 2; ++kc)
    aq[kc] = *(const bf16x8*)&qb[qkbase + (size_t)(q0 + l15) * HD + kc * 32 + g * 8];

  f32x4 accs[5];
#pragma unroll
  for (int tt = 0; tt < 5; ++tt) accs[tt] = (f32x4){0.f, 0.f, 0.f, 0.f};

#pragma unroll
  for (int tt = 0; tt < 5; ++tt) {
    const int krow = q0 - 32 + tt * 16 + l15;
    bf16x8 bk0 = (bf16x8){0, 0, 0, 0, 0, 0, 0, 0};
    bf16x8 bk1 = bk0;
    if (krow >= 0 && krow < SEQ) {
      bk0 = *(const bf16x8*)&kb[qkbase + (size_t)krow * HD + g * 8];
      bk1 = *(const bf16x8*)&kb[qkbase + (size_t)krow * HD + 32 + g * 8];
    }
    accs[tt] = __builtin_amdgcn_mfma_f32_16x16x32_bf16(aq[0], bk0, accs[tt], 0, 0, 0);
    accs[tt] = __builtin_amdgcn_mfma_f32_16x16x32_bf16(aq[1], bk1, accs[tt], 0, 0, 0);
  }

  // ---- softmax over w = c - i in [0,64]; C layout: col c = 16t+l15, row i = 4g+j ----
#pragma unroll
  for (int tt = 0; tt < 5; ++tt)
#pragma unroll
    for (int j = 0; j < 4; ++j) {
      const int w = tt * 16 + l15 - (4 * g + j);
      if (!(w >= 0 && w <= 64)) accs[tt][j] = -3.0e38f;
    }
  float mj[4], invj[4];
#pragma unroll
  for (int j = 0; j < 4; ++j) {
    float m = fmaxf(fmaxf(fmaxf(accs[0][j], accs[1][j]), fmaxf(accs[2][j], accs[3][j])), accs[4][j]);
#pragma unroll
    for (int o = 8; o; o >>= 1) m = fmaxf(m, __shfl_xor(m, o));
    mj[j] = m;
  }
#pragma unroll
  for (int tt = 0; tt < 5; ++tt)
#pragma unroll
    for (int j = 0; j < 4; ++j)
      accs[tt][j] = (accs[tt][j] > -1.0e38f) ? __expf(accs[tt][j] - mj[j]) : 0.f;
#pragma unroll
  for (int j = 0; j < 4; ++j) {
    float s = accs[0][j] + accs[1][j] + accs[2][j] + accs[3][j] + accs[4][j];
#pragma unroll
    for (int o = 8; o; o >>= 1) s += __shfl_xor(s, o);
    invj[j] = 1.f / s;
  }
  const size_t abase = (size_t)bh * SEQ;
#pragma unroll
  for (int tt = 0; tt < 5; ++tt)
#pragma unroll
    for (int j = 0; j < 4; ++j) {
      const int i = 4 * g + j;
      const int w = tt * 16 + l15 - i;
      const float a = accs[tt][j] * invj[j];
      if (w >= 0 && w <= 64)
        attn_out[(abase + q0 + i) * WIN + w] = a;
      Plds[wv][i][tt * 16 + l15] = f2bf(a);
    }
#pragma unroll
  for (int j = 0; j < 4; ++j) Plds[wv][4 * g + j][80 + l15] = 0;

  // ---- PV: ctx[i][d] = sum_c P[i][c] * V[q0-32+c][d], via VT (bh,d,n) ----
  f32x4 accc[4];
#pragma unroll
  for (int dt = 0; dt < 4; ++dt) accc[dt] = (f32x4){0.f, 0.f, 0.f, 0.f};
#pragma unroll
  for (int kc = 0; kc < 3; ++kc) {
    const bf16x8 pa = *(const bf16x8*)&Plds[wv][l15][kc * 32 + g * 8];
    const int nb = q0 - 32 + kc * 32 + g * 8;   // multiple of 8: chunks all-in or all-out
    const bool inr = (nb >= 0 && nb < SEQ);
#pragma unroll
    for (int dt = 0; dt < 4; ++dt) {
      bf16x8 bv = (bf16x8){0, 0, 0, 0, 0, 0, 0, 0};
      if (inr) bv = *(const bf16x8*)&vt[((size_t)bh * HD + dt * 16 + l15) * SEQ + nb];
      accc[dt] = __builtin_amdgcn_mfma_f32_16x16x32_bf16(pa, bv, accc[dt], 0, 0, 0);
    }
  }
  const int b = bh >> 3, h = bh & 7;
#pragma unroll
  for (int dt = 0; dt < 4; ++dt)
#pragma unroll
    for (int j = 0; j < 4; ++j)
      ctxb[((size_t)(b * SEQ + q0 + 4 * g + j)) * DM + h * HD + dt * 16 + l15] = f2bf(accc[dt][j]);
}

extern "C" void kernel_launch(void* const* d_in, const int* in_sizes, int n_in,
                              void* d_out, int out_size, void* d_ws, size_t ws_size,
                              hipStream_t stream) {
  const float* x  = (const float*)d_in[0];
  const float* Wq = (const float*)d_in[1];
  const float* Wk = (const float*)d_in[2];
  const float* Wv = (const float*)d_in[3];
  const float* Wo = (const float*)d_in[4];
  const float* bq = (const float*)d_in[5];
  const float* bk = (const float*)d_in[6];
  const float* bv = (const float*)d_in[7];
  const float* bo = (const float*)d_in[8];

  float* out = (float*)d_out;                        // (B, N, 512) f32
  float* attn_out = out + (size_t)8192 * 512;        // (B, H, N, 65) f32

  char* ws = (char*)d_ws;
  unsigned short* xb   = (unsigned short*)ws;                       // 8,388,608 B
  unsigned short* wt   = (unsigned short*)(ws + 8388608);           // 2,097,152 B (Wq,Wk,Wv,Wo transposed bf16)
  unsigned short* qkv  = (unsigned short*)(ws + 10485760);          // 25,165,824 B (q,k head-major; vt transposed)
  unsigned short* ctxb = (unsigned short*)(ws + 35651584);          // 8,388,608 B (ctx bf16, (B,N,512))

  conv_x_kernel<<<dim3(4096), dim3(256), 0, stream>>>(x, xb, 1048576);
  conv_wt_kernel<<<dim3(8, 8, 4), dim3(256), 0, stream>>>(Wq, Wk, Wv, Wo, wt);
  gemm_kernel<0><<<dim3(64, 4, 3), dim3(256), 0, stream>>>(xb, wt, bq, bk, bv, (void*)qkv);
  attn_kernel<<<dim3(32, 16), dim3(512), 0, stream>>>(
      qkv, qkv + 4194304, qkv + 8388608, attn_out, ctxb);
  gemm_kernel<1><<<dim3(64, 4, 1), dim3(256), 0, stream>>>(ctxb, wt + 3 * 262144, bo, nullptr, nullptr, (void*)out);
}